// Round 4
// baseline (78.161 us; speedup 1.0000x reference)
//
#include <hip/hip_runtime.h>
#include <hip/hip_fp16.h>

typedef _Float16 f16;
typedef _Float16 f16x8 __attribute__((ext_vector_type(8)));
typedef float f32x16 __attribute__((ext_vector_type(16)));

#define NEGV (-1e30f)

constexpr int T_    = 8192;
constexpr int BATCH = 4;
constexpr int D_    = 1024;   // K
constexpr int ROWS  = BATCH * T_;   // 32768
constexpr int BM    = 128;
constexpr int BK    = 64;
constexpr int KT    = D_ / BK;      // 16
constexpr int NWG   = ROWS / BM;    // 256
constexpr int NTHR  = 512;

// ws layout: [0,1MB) swizzled f16 weights (per kt: 64KB tile, byte = col*128 + ((2k)^((col&7)<<4)))
//            [1MB,2MB) boundary floats: bound[g][2][4][128]  (half0=Cb, half1=Zb)
#define BOUND_OFF (1u << 20)

__device__ __forceinline__ void gload_lds16(const void* g, void* l) {
  __builtin_amdgcn_global_load_lds(
      (const __attribute__((address_space(1))) void*)g,
      (__attribute__((address_space(3))) void*)l, 16, 0, 0);
}

// ---------------- prep: weight convert+swizzle, boundary rows ----------------
__global__ __launch_bounds__(1024) void tc_prep(
    const float* __restrict__ H,
    const float* __restrict__ Wakv, const float* __restrict__ Wbkv,
    const float* __restrict__ Waz,  const float* __restrict__ Wbz,
    unsigned char* __restrict__ ws)
{
  const int b = blockIdx.x, t = threadIdx.x;
  if (b < NWG) {
    float* bound = (float*)(ws + BOUND_OFF) + (long long)b * 1024;
    if ((b & 63) == 0) {
      bound[t] = (t < 512) ? 0.f : NEGV;
      return;
    }
    __shared__ float hrow[4][1024];        // 16 KB
    __shared__ float part[8][8][128];      // 32 KB
    const long long R0 = (long long)b * BM - 4;
    for (int i = t; i < 4096; i += 1024) hrow[i >> 10][i & 1023] = H[R0 * D_ + i];
    __syncthreads();

    const int j  = t & 127;
    const int kc = t >> 7;
    const int k0 = kc * 128;
    float acc[2][4] = {{0.f,0.f,0.f,0.f},{0.f,0.f,0.f,0.f}};
#pragma unroll 4
    for (int k = k0; k < k0 + 128; ++k) {
      const float w0 = Wbkv[k*128 + j];
      const float w1 = Wbz [k*128 + j];
#pragma unroll
      for (int m = 0; m < 4; ++m) {
        const float hv = hrow[m][k];
        acc[0][m] += hv * w0;
        acc[1][m] += hv * w1;
      }
    }
#pragma unroll
    for (int half = 0; half < 2; ++half)
#pragma unroll
      for (int m = 0; m < 4; ++m) part[kc][half*4 + m][j] = acc[half][m];
    __syncthreads();
    {
      const int half = t >> 9, rm = (t >> 7) & 3, jj = t & 127;
      float s = 0.f;
#pragma unroll
      for (int kk = 0; kk < 8; ++kk) s += part[kk][half*4 + rm][jj];
      bound[t] = s;
    }
  } else {
    const int u   = (b - NWG) * 1024 + t;
    const int kt  = u >> 12;
    const int rem = u & 4095;
    const int k8  = rem >> 9;
    const int col = rem & 511;
    const int mat = col >> 7, j = col & 127;
    const float* Wm = (mat == 0) ? Wakv : (mat == 1) ? Wbkv : (mat == 2) ? Waz : Wbz;
    f16x8 v;
#pragma unroll
    for (int e = 0; e < 8; ++e) v[e] = (f16)Wm[(kt*64 + k8*8 + e)*128 + j];
    *(f16x8*)(ws + (size_t)kt*65536 + col*128 + ((k8*16) ^ ((col & 7) << 4))) = v;
  }
}

// ---------------- main fused kernel (2-phase-per-K-step schedule) ----------------
__global__ __launch_bounds__(NTHR, 2) void tc_main(
    const float* __restrict__ H,
    const float* __restrict__ Ba,
    const float* __restrict__ Bbb,
    const unsigned char* __restrict__ ws,
    float* __restrict__ out)
{
  // full dbuf A+B: 2*16KB + 2*64KB = 160 KB (HW max)
  __shared__ __align__(16) unsigned char lds[163840];

  const int tid  = threadIdx.x;
  const int w    = tid >> 6;
  const int lane = tid & 63;
  const int g    = blockIdx.x;
  const long long R0 = (long long)g * BM;

  f32x16 acc[2][4];
#pragma unroll
  for (int i = 0; i < 2; ++i)
#pragma unroll
    for (int jq = 0; jq < 4; ++jq)
#pragma unroll
      for (int e = 0; e < 16; ++e) acc[i][jq][e] = 0.f;

  // --- A staging indices
  const int ar   = tid >> 2;
  const int akq  = tid & 3;
  const float* aptr = H + (R0 + ar) * D_ + akq * 16;
  const int abase = ar * 128;
  const int aswz  = (ar & 7) << 4;

  // --- compute-phase per-wave constants
  const int whalf = w >> 2;
  const int jpos  = w & 3;
  const int mrow  = lane & 31;
  const int kq2   = (lane >> 5) * 16;
  const int axor  = (mrow & 7) << 4;
  const int arow0 = (whalf*64 + mrow) * 128;
  const int arow1 = arow0 + 32*128;
  const int jb    = (jpos*32 + mrow) * 128;

  float4 areg[4];
  f16x8 ra0[2], ra1[2], rb[2][4];

#define SA_OFF(IDX) ((IDX) * 16384)
#define SB_OFF(IDX) (32768 + (IDX) * 65536)

#define STAGE_B(KTN, DSTOFF)                                                     \
  { _Pragma("unroll")                                                            \
    for (int r = 0; r < 8; ++r)                                                  \
      gload_lds16(ws + (size_t)(KTN)*65536 + w*1024 + r*8192 + lane*16,          \
                  lds + (DSTOFF) + w*1024 + r*8192); }

#define LOAD_AREG(KTN)                                                           \
  { const float4* p = (const float4*)(aptr + (KTN) * 64);                        \
    areg[0] = p[0]; areg[1] = p[1]; areg[2] = p[2]; areg[3] = p[3]; }

#define WRITE_A(DSTOFF)                                                          \
  { f16x8 v0, v1; const float* af = (const float*)areg;                          \
    _Pragma("unroll")                                                            \
    for (int e = 0; e < 8; ++e) { v0[e] = (f16)af[e]; v1[e] = (f16)af[8 + e]; }  \
    *(f16x8*)(lds + (DSTOFF) + abase + ((akq*32)      ^ aswz)) = v0;             \
    *(f16x8*)(lds + (DSTOFF) + abase + ((akq*32 + 16) ^ aswz)) = v1; }

#define READ_SUBS(SAOFF, SBOFF, KF0)                                             \
  { _Pragma("unroll")                                                            \
    for (int kk = 0; kk < 2; ++kk) {                                             \
      const int ko = ((((KF0) + kk)*32 + kq2) ^ axor);                           \
      ra0[kk] = *(const f16x8*)(lds + (SAOFF) + arow0 + ko);                     \
      ra1[kk] = *(const f16x8*)(lds + (SAOFF) + arow1 + ko);                     \
      _Pragma("unroll")                                                          \
      for (int gr = 0; gr < 4; ++gr)                                             \
        rb[kk][gr] = *(const f16x8*)(lds + (SBOFF) + gr*16384 + jb + ko); } }

#define MFMA_SUBS()                                                              \
  { _Pragma("unroll")                                                            \
    for (int kk = 0; kk < 2; ++kk)                                               \
      _Pragma("unroll")                                                          \
      for (int gr = 0; gr < 4; ++gr) {                                           \
        acc[0][gr] = __builtin_amdgcn_mfma_f32_32x32x16_f16(ra0[kk], rb[kk][gr], acc[0][gr], 0, 0, 0); \
        acc[1][gr] = __builtin_amdgcn_mfma_f32_32x32x16_f16(ra1[kk], rb[kk][gr], acc[1][gr], 0, 0, 0); } }

  // ---- prologue: stage tile 0 ----
  LOAD_AREG(0);
  __builtin_amdgcn_sched_barrier(0);
  STAGE_B(0, SB_OFF(0));
  WRITE_A(SA_OFF(0));                     // compiler emits exact vmcnt wait for areg
  asm volatile("s_waitcnt vmcnt(0) lgkmcnt(0)" ::: "memory");
  __builtin_amdgcn_sched_barrier(0);
  __builtin_amdgcn_s_barrier();

  for (int kt = 0; kt < KT; ++kt) {
    const int cur = kt & 1, nxt = cur ^ 1;
    const int ktn = (kt + 1) & (KT - 1);   // kt==15 wraps: harmless re-stage of tile 0
    const int saOff = SA_OFF(cur), sbOff = SB_OFF(cur);

    // ================= phase A: subs {0,1} =================
    LOAD_AREG(ktn);                        // issue-early (T14)
    __builtin_amdgcn_sched_barrier(0);
    STAGE_B(ktn, SB_OFF(nxt));
    READ_SUBS(saOff, sbOff, 0);
    __builtin_amdgcn_s_barrier();
    asm volatile("s_waitcnt lgkmcnt(0)" ::: "memory");
    __builtin_amdgcn_sched_barrier(0);
    __builtin_amdgcn_s_setprio(1);
    MFMA_SUBS();
    __builtin_amdgcn_s_setprio(0);
    __builtin_amdgcn_sched_barrier(0);
    __builtin_amdgcn_s_barrier();

    // ================= phase B: subs {2,3} =================
    READ_SUBS(saOff, sbOff, 2);
    WRITE_A(SA_OFF(nxt));                  // write-late; compiler waits areg exactly
    asm volatile("s_waitcnt vmcnt(0) lgkmcnt(0)" ::: "memory");  // B(kt+1) DMA + my ds ops done
    __builtin_amdgcn_sched_barrier(0);
    __builtin_amdgcn_s_barrier();
    __builtin_amdgcn_sched_barrier(0);
    __builtin_amdgcn_s_setprio(1);
    MFMA_SUBS();
    __builtin_amdgcn_s_setprio(0);
    __builtin_amdgcn_sched_barrier(0);
    __builtin_amdgcn_s_barrier();          // protects buf[cur] from next iter's staging
  }

  // ---------------- epilogue ----------------
  float* eCb = (float*)lds;               // [128][128]
  float* eZb = (float*)(lds + 65536);     // [128][128]
  const int jj = jpos*32 + mrow;
  const int h  = lane >> 5;

#pragma unroll
  for (int rf = 0; rf < 2; ++rf)
#pragma unroll
    for (int r = 0; r < 16; ++r) {
      const int row = whalf*64 + rf*32 + (r & 3) + 8*(r >> 2) + 4*h;
      eCb[row*128 + jj] = acc[rf][1][r];
      eZb[row*128 + jj] = acc[rf][3][r];
    }
  __syncthreads();

  float bav[4], bbv[4];
#pragma unroll
  for (int m = 0; m < 4; ++m) { bav[m] = Ba[m*128 + jj]; bbv[m] = Bbb[m*128 + jj]; }
  const float* bound = (const float*)(ws + BOUND_OFF) + (long long)g * 1024;

#pragma unroll
  for (int rf = 0; rf < 2; ++rf)
#pragma unroll
    for (int q = 0; q < 4; ++q) {
      const int bf = 2*q + h;
      const int bl = whalf*16 + rf*8 + bf;
      float za[4], ca[4], zb[4], cb[4];
#pragma unroll
      for (int m = 0; m < 4; ++m) {
        za[m] = acc[rf][2][q*4 + m] + bav[m];
        ca[m] = acc[rf][0][q*4 + m];
      }
      if (bl == 0) {
#pragma unroll
        for (int m = 0; m < 4; ++m) {
          cb[m] = bound[m*128 + jj];
          zb[m] = bound[512 + m*128 + jj] + bbv[m];
        }
      } else {
#pragma unroll
        for (int m = 0; m < 4; ++m) {
          const int pr = bl*4 - 4 + m;
          cb[m] = eCb[pr*128 + jj];
          zb[m] = eZb[pr*128 + jj] + bbv[m];
        }
      }
      float mx = za[0];
#pragma unroll
      for (int m = 1; m < 4; ++m) mx = fmaxf(mx, za[m]);
#pragma unroll
      for (int m = 0; m < 4; ++m) mx = fmaxf(mx, zb[m]);
      float s = 0.f, o = 0.f;
#pragma unroll
      for (int m = 0; m < 4; ++m) {
        const float ea = __expf(za[m] - mx);
        const float eb = __expf(zb[m] - mx);
        s += ea + eb;
        o += ea*ca[m] + eb*cb[m];
      }
      out[((long long)g*32 + bl)*128 + jj] = o / s;
    }
}

extern "C" void kernel_launch(void* const* d_in, const int* in_sizes, int n_in,
                              void* d_out, int out_size, void* d_ws, size_t ws_size,
                              hipStream_t stream) {
  const float* H    = (const float*)d_in[0];
  const float* Wakv = (const float*)d_in[1];
  const float* Wbkv = (const float*)d_in[2];
  const float* Waz  = (const float*)d_in[3];
  const float* Wbz  = (const float*)d_in[4];
  const float* Ba   = (const float*)d_in[5];
  const float* Bbb  = (const float*)d_in[6];
  float* out        = (float*)d_out;
  unsigned char* ws = (unsigned char*)d_ws;

  tc_prep<<<NWG + 64, 1024, 0, stream>>>(H, Wakv, Wbkv, Waz, Wbz, ws);
  tc_main<<<NWG, NTHR, 0, stream>>>(H, Ba, Bbb, ws, out);
}

// Round 5
// 69.393 us; speedup vs baseline: 1.1264x; 1.1264x over previous
//
#include <hip/hip_runtime.h>
#include <hip/hip_fp16.h>

typedef _Float16 f16;
typedef _Float16 f16x8 __attribute__((ext_vector_type(8)));
typedef float f32x16 __attribute__((ext_vector_type(16)));

#define NEGV (-1e30f)

constexpr int T_    = 8192;
constexpr int BATCH = 4;
constexpr int D_    = 1024;   // K
constexpr int ROWS  = BATCH * T_;   // 32768
constexpr int BM    = 128;
constexpr int BK    = 64;
constexpr int KT    = D_ / BK;      // 16
constexpr int NWG   = ROWS / BM;    // 256
constexpr int NTHR  = 512;

// ws layout: [0,1MB) swizzled f16 weights; [1MB,2MB) boundary floats bound[g][2][4][128]
#define BOUND_OFF (1u << 20)

__device__ __forceinline__ void gload_lds16(const void* g, void* l) {
  __builtin_amdgcn_global_load_lds(
      (const __attribute__((address_space(1))) void*)g,
      (__attribute__((address_space(3))) void*)l, 16, 0, 0);
}

// ---------------- prep: weight convert+swizzle, boundary rows ----------------
__global__ __launch_bounds__(1024) void tc_prep(
    const float* __restrict__ H,
    const float* __restrict__ Wakv, const float* __restrict__ Wbkv,
    const float* __restrict__ Waz,  const float* __restrict__ Wbz,
    unsigned char* __restrict__ ws)
{
  const int b = blockIdx.x, t = threadIdx.x;
  if (b < NWG) {
    float* bound = (float*)(ws + BOUND_OFF) + (long long)b * 1024;
    if ((b & 63) == 0) {
      bound[t] = (t < 512) ? 0.f : NEGV;
      return;
    }
    __shared__ float hrow[4][1024];        // 16 KB
    __shared__ float part[8][8][128];      // 32 KB
    const long long R0 = (long long)b * BM - 4;
    for (int i = t; i < 4096; i += 1024) hrow[i >> 10][i & 1023] = H[R0 * D_ + i];
    __syncthreads();

    const int j  = t & 127;
    const int kc = t >> 7;
    const int k0 = kc * 128;
    float acc[2][4] = {{0.f,0.f,0.f,0.f},{0.f,0.f,0.f,0.f}};
#pragma unroll 4
    for (int k = k0; k < k0 + 128; ++k) {
      const float w0 = Wbkv[k*128 + j];
      const float w1 = Wbz [k*128 + j];
#pragma unroll
      for (int m = 0; m < 4; ++m) {
        const float hv = hrow[m][k];
        acc[0][m] += hv * w0;
        acc[1][m] += hv * w1;
      }
    }
#pragma unroll
    for (int half = 0; half < 2; ++half)
#pragma unroll
      for (int m = 0; m < 4; ++m) part[kc][half*4 + m][j] = acc[half][m];
    __syncthreads();
    {
      const int half = t >> 9, rm = (t >> 7) & 3, jj = t & 127;
      float s = 0.f;
#pragma unroll
      for (int kk = 0; kk < 8; ++kk) s += part[kk][half*4 + rm][jj];
      bound[t] = s;
    }
  } else {
    const int u   = (b - NWG) * 1024 + t;
    const int kt  = u >> 12;
    const int rem = u & 4095;
    const int k8  = rem >> 9;
    const int col = rem & 511;
    const int mat = col >> 7, j = col & 127;
    const float* Wm = (mat == 0) ? Wakv : (mat == 1) ? Wbkv : (mat == 2) ? Waz : Wbz;
    f16x8 v;
#pragma unroll
    for (int e = 0; e < 8; ++e) v[e] = (f16)Wm[(kt*64 + k8*8 + e)*128 + j];
    *(f16x8*)(ws + (size_t)kt*65536 + col*128 + ((k8*16) ^ ((col & 7) << 4))) = v;
  }
}

// ---------------- main fused kernel (m201-style 4-phase K-step) ----------------
__global__ __launch_bounds__(NTHR, 2) void tc_main(
    const float* __restrict__ H,
    const float* __restrict__ Ba,
    const float* __restrict__ Bbb,
    const unsigned char* __restrict__ ws,
    float* __restrict__ out)
{
  __shared__ __align__(16) unsigned char lds[163840];   // 2*16K A + 2*64K B

  const int tid  = threadIdx.x;
  const int w    = tid >> 6;
  const int lane = tid & 63;
  const int g    = blockIdx.x;
  const long long R0 = (long long)g * BM;

  f32x16 acc[2][4];
#pragma unroll
  for (int i = 0; i < 2; ++i)
#pragma unroll
    for (int jq = 0; jq < 4; ++jq)
#pragma unroll
      for (int e = 0; e < 16; ++e) acc[i][jq][e] = 0.f;

  // --- A staging indices
  const int ar   = tid >> 2;
  const int akq  = tid & 3;
  const float* aptr = H + (R0 + ar) * D_ + akq * 16;
  const int abase = ar * 128;
  const int aswz  = (ar & 7) << 4;

  // --- compute-phase per-wave constants
  const int whalf = w >> 2;
  const int jpos  = w & 3;
  const int mrow  = lane & 31;
  const int kq2   = (lane >> 5) * 16;
  const int axor  = (mrow & 7) << 4;
  const int arow0 = (whalf*64 + mrow) * 128;
  const int arow1 = arow0 + 32*128;
  const int jb    = (jpos*32 + mrow) * 128;

  float4 areg0[4], areg1[4];      // 2-deep A staging, statically named
  f16x8 ra0, ra1, rb0, rb1, rb2, rb3;

#define SA_OFF(IDX) ((IDX) * 16384)
#define SB_OFF(IDX) (32768 + (IDX) * 65536)

#define STAGE_B4(KTN, DSTOFF, RBASE)                                             \
  { _Pragma("unroll")                                                            \
    for (int r = (RBASE); r < (RBASE) + 4; ++r)                                  \
      gload_lds16(ws + (size_t)(KTN)*65536 + w*1024 + r*8192 + lane*16,          \
                  lds + (DSTOFF) + w*1024 + r*8192); }

#define LOAD_AREG(KTN, A)                                                        \
  { const float4* p = (const float4*)(aptr + (KTN) * 64);                        \
    A[0] = p[0]; A[1] = p[1]; A[2] = p[2]; A[3] = p[3]; }

#define WRITE_A(DSTOFF, A)                                                       \
  { f16x8 v0, v1; const float* af = (const float*)A;                             \
    _Pragma("unroll")                                                            \
    for (int e = 0; e < 8; ++e) { v0[e] = (f16)af[e]; v1[e] = (f16)af[8 + e]; }  \
    *(f16x8*)(lds + (DSTOFF) + abase + ((akq*32)      ^ aswz)) = v0;             \
    *(f16x8*)(lds + (DSTOFF) + abase + ((akq*32 + 16) ^ aswz)) = v1; }

#define READ_SUB(SAOFF, SBOFF, P)                                                \
  { const int ko = (((P)*32 + kq2) ^ axor);                                      \
    ra0 = *(const f16x8*)(lds + (SAOFF) + arow0 + ko);                           \
    ra1 = *(const f16x8*)(lds + (SAOFF) + arow1 + ko);                           \
    rb0 = *(const f16x8*)(lds + (SBOFF) + 0*16384 + jb + ko);                    \
    rb1 = *(const f16x8*)(lds + (SBOFF) + 1*16384 + jb + ko);                    \
    rb2 = *(const f16x8*)(lds + (SBOFF) + 2*16384 + jb + ko);                    \
    rb3 = *(const f16x8*)(lds + (SBOFF) + 3*16384 + jb + ko); }

#define MFMA_SUB()                                                               \
  { acc[0][0] = __builtin_amdgcn_mfma_f32_32x32x16_f16(ra0, rb0, acc[0][0], 0,0,0); \
    acc[1][0] = __builtin_amdgcn_mfma_f32_32x32x16_f16(ra1, rb0, acc[1][0], 0,0,0); \
    acc[0][1] = __builtin_amdgcn_mfma_f32_32x32x16_f16(ra0, rb1, acc[0][1], 0,0,0); \
    acc[1][1] = __builtin_amdgcn_mfma_f32_32x32x16_f16(ra1, rb1, acc[1][1], 0,0,0); \
    acc[0][2] = __builtin_amdgcn_mfma_f32_32x32x16_f16(ra0, rb2, acc[0][2], 0,0,0); \
    acc[1][2] = __builtin_amdgcn_mfma_f32_32x32x16_f16(ra1, rb2, acc[1][2], 0,0,0); \
    acc[0][3] = __builtin_amdgcn_mfma_f32_32x32x16_f16(ra0, rb3, acc[0][3], 0,0,0); \
    acc[1][3] = __builtin_amdgcn_mfma_f32_32x32x16_f16(ra1, rb3, acc[1][3], 0,0,0); }

#define PHASE_TAIL()                                                             \
  __builtin_amdgcn_sched_barrier(0);                                             \
  __builtin_amdgcn_s_barrier();                                                  \
  asm volatile("s_waitcnt lgkmcnt(0)" ::: "memory");                             \
  __builtin_amdgcn_sched_barrier(0);                                             \
  __builtin_amdgcn_s_setprio(1)

#define PHASE_END()                                                              \
  __builtin_amdgcn_s_setprio(0);                                                 \
  __builtin_amdgcn_sched_barrier(0);                                             \
  __builtin_amdgcn_s_barrier();                                                  \
  __builtin_amdgcn_sched_barrier(0)

// One K-step = 4 phases (p = k-frag). Staging: B gloads split 4+4 over phases
// 0-1; A global load (tile kt+2) at phase 2; A ds_write (tile kt+1) at phase 3.
// Only vmem wait: vmcnt(4) at phase 3 — drains the 8 B DMAs, keeps A in flight.
#define KSTEP(SAC, SBC, SAN, SBN, KTN, KT2, AL, AW)                              \
  READ_SUB(SAC, SBC, 0);                                                         \
  STAGE_B4(KTN, SBN, 0);                                                         \
  PHASE_TAIL(); MFMA_SUB(); PHASE_END();                                         \
  READ_SUB(SAC, SBC, 1);                                                         \
  STAGE_B4(KTN, SBN, 4);                                                         \
  PHASE_TAIL(); MFMA_SUB(); PHASE_END();                                         \
  READ_SUB(SAC, SBC, 2);                                                         \
  LOAD_AREG(KT2, AL);                                                            \
  PHASE_TAIL(); MFMA_SUB(); PHASE_END();                                         \
  READ_SUB(SAC, SBC, 3);                                                         \
  WRITE_A(SAN, AW);                                                              \
  asm volatile("s_waitcnt vmcnt(4)" ::: "memory");                               \
  PHASE_TAIL(); MFMA_SUB(); PHASE_END()

  // ---- prologue: stage tile 0, preload A(1) ----
  LOAD_AREG(0, areg0);
  __builtin_amdgcn_sched_barrier(0);
  STAGE_B4(0, SB_OFF(0), 0);
  STAGE_B4(0, SB_OFF(0), 4);
  WRITE_A(SA_OFF(0), areg0);              // compiler emits exact vmcnt for areg0
  LOAD_AREG(1, areg1);
  asm volatile("s_waitcnt vmcnt(4) lgkmcnt(0)" ::: "memory");
  __builtin_amdgcn_sched_barrier(0);
  __builtin_amdgcn_s_barrier();
  __builtin_amdgcn_sched_barrier(0);

  for (int kt = 0; kt < KT; kt += 2) {
    const int ktn  = kt + 1;
    const int kt2  = (kt + 2) & (KT - 1);
    const int kt3  = (kt + 3) & (KT - 1);
    KSTEP(SA_OFF(0), SB_OFF(0), SA_OFF(1), SB_OFF(1), ktn, kt2, areg0, areg1);
    KSTEP(SA_OFF(1), SB_OFF(1), SA_OFF(0), SB_OFF(0), kt2, kt3, areg1, areg0);
  }

  // drain wrap-issued vmem before reusing LDS
  asm volatile("s_waitcnt vmcnt(0)" ::: "memory");
  __builtin_amdgcn_s_barrier();

  // ---------------- epilogue ----------------
  float* eCb = (float*)lds;               // [128][128]
  float* eZb = (float*)(lds + 65536);     // [128][128]
  const int jj = jpos*32 + mrow;
  const int h  = lane >> 5;

#pragma unroll
  for (int rf = 0; rf < 2; ++rf)
#pragma unroll
    for (int r = 0; r < 16; ++r) {
      const int row = whalf*64 + rf*32 + (r & 3) + 8*(r >> 2) + 4*h;
      eCb[row*128 + jj] = acc[rf][1][r];
      eZb[row*128 + jj] = acc[rf][3][r];
    }
  __syncthreads();

  float bav[4], bbv[4];
#pragma unroll
  for (int m = 0; m < 4; ++m) { bav[m] = Ba[m*128 + jj]; bbv[m] = Bbb[m*128 + jj]; }
  const float* bound = (const float*)(ws + BOUND_OFF) + (long long)g * 1024;

#pragma unroll
  for (int rf = 0; rf < 2; ++rf)
#pragma unroll
    for (int q = 0; q < 4; ++q) {
      const int bf = 2*q + h;
      const int bl = whalf*16 + rf*8 + bf;
      float za[4], ca[4], zb[4], cb[4];
#pragma unroll
      for (int m = 0; m < 4; ++m) {
        za[m] = acc[rf][2][q*4 + m] + bav[m];
        ca[m] = acc[rf][0][q*4 + m];
      }
      if (bl == 0) {
#pragma unroll
        for (int m = 0; m < 4; ++m) {
          cb[m] = bound[m*128 + jj];
          zb[m] = bound[512 + m*128 + jj] + bbv[m];
        }
      } else {
#pragma unroll
        for (int m = 0; m < 4; ++m) {
          const int pr = bl*4 - 4 + m;
          cb[m] = eCb[pr*128 + jj];
          zb[m] = eZb[pr*128 + jj] + bbv[m];
        }
      }
      float mx = za[0];
#pragma unroll
      for (int m = 1; m < 4; ++m) mx = fmaxf(mx, za[m]);
#pragma unroll
      for (int m = 0; m < 4; ++m) mx = fmaxf(mx, zb[m]);
      float s = 0.f, o = 0.f;
#pragma unroll
      for (int m = 0; m < 4; ++m) {
        const float ea = __expf(za[m] - mx);
        const float eb = __expf(zb[m] - mx);
        s += ea + eb;
        o += ea*ca[m] + eb*cb[m];
      }
      out[((long long)g*32 + bl)*128 + jj] = o / s;
    }
}

extern "C" void kernel_launch(void* const* d_in, const int* in_sizes, int n_in,
                              void* d_out, int out_size, void* d_ws, size_t ws_size,
                              hipStream_t stream) {
  const float* H    = (const float*)d_in[0];
  const float* Wakv = (const float*)d_in[1];
  const float* Wbkv = (const float*)d_in[2];
  const float* Waz  = (const float*)d_in[3];
  const float* Wbz  = (const float*)d_in[4];
  const float* Ba   = (const float*)d_in[5];
  const float* Bbb  = (const float*)d_in[6];
  float* out        = (float*)d_out;
  unsigned char* ws = (unsigned char*)d_ws;

  tc_prep<<<NWG + 64, 1024, 0, stream>>>(H, Wakv, Wbkv, Waz, Wbz, ws);
  tc_main<<<NWG, NTHR, 0, stream>>>(H, Ba, Bbb, ws, out);
}